// Round 2
// baseline (189.792 us; speedup 1.0000x reference)
//
#include <hip/hip_runtime.h>

namespace {
constexpr int KS   = 5;    // reassembly kernel
constexpr int UWF  = 3;    // upsample factor (width)
constexpr int HID_ = 64;
constexpr int BB   = 4, HH = 512, WW_ = 512;
constexpr int HW   = HH * WW_;
constexpr int OW   = WW_ * UWF;          // 1536
constexpr int OPL  = HH * OW;            // out plane 786432
}

__global__ __launch_bounds__(256) void xg_mean_kernel(const float* __restrict__ x,
                                                      float* __restrict__ xg) {
    int idx = blockIdx.x * 256 + threadIdx.x;   // over B*H*W, grid exact
    int b  = idx >> 18;
    int hw = idx & (HW - 1);
    const float* xb = x + (size_t)b * 3 * HW;
    xg[idx] = (xb[hw] + xb[HW + hw] + xb[2 * HW + hw]) * (1.0f / 3.0f);
}

// 2 waves/EU min -> up to ~256 VGPRs/wave: keeps hb[64]+xw[25] in VGPRs (no AGPR spill)
template <bool USE_WS>
__global__ __launch_bounds__(256, 2) void carafe_fused_kernel(
    const float* __restrict__ x, const float* __restrict__ xg,
    const float* __restrict__ w1, const float* __restrict__ b1,
    const float* __restrict__ w2, const float* __restrict__ b2,
    const float* __restrict__ wp, const float* __restrict__ bp,
    float* __restrict__ out) {
  int idx = blockIdx.x * 256 + threadIdx.x;     // over B*H*W, grid exact
  int b  = idx >> 18;
  int hw = idx & (HW - 1);
  int h  = hw >> 9;
  int w  = hw & (WW_ - 1);

  float wps = wp[0], bps = bp[0];

  // 5x5 xg window (zero-padded), covers both the 3x3 conv and the reassembly taps
  float xw[KS][KS];
#pragma unroll
  for (int dy = 0; dy < KS; ++dy) {
    int y = h + dy - 2;
    bool yok = ((unsigned)y < (unsigned)HH);
#pragma unroll
    for (int dx = 0; dx < KS; ++dx) {
      int xc = w + dx - 2;
      bool ok = yok && ((unsigned)xc < (unsigned)WW_);
      float v = 0.0f;
      if (ok) {
        if (USE_WS) {
          v = xg[(size_t)b * HW + y * WW_ + xc];
        } else {
          const float* xb = x + (size_t)b * 3 * HW + y * WW_ + xc;
          v = (xb[0] + xb[HW] + xb[2 * HW]) * (1.0f / 3.0f);
        }
      }
      xw[dy][dx] = v;
    }
  }

  // 3x3 conv (centered) + ReLU -> 64 hidden (kept in VGPRs)
  float hb[HID_];
#pragma unroll
  for (int c = 0; c < HID_; ++c) {
    float acc = b1[c];
#pragma unroll
    for (int ky = 0; ky < 3; ++ky)
#pragma unroll
      for (int kx = 0; kx < 3; ++kx)
        acc = fmaf(xw[1 + ky][1 + kx], w1[c * 9 + ky * 3 + kx], acc);
    hb[c] = fmaxf(acc, 0.0f);
  }

  // 1x1 conv -> 75 logits; streaming softmax (no max-sub: |logit| << 1) + reassembly
  float accv[UWF] = {0.f, 0.f, 0.f};
  float sumv[UWF] = {0.f, 0.f, 0.f};
#pragma unroll
  for (int kk = 0; kk < KS * KS; ++kk) {
    float nv = xw[kk / KS][kk % KS];
#pragma unroll
    for (int v = 0; v < UWF; ++v) {
      int ch = kk * UWF + v;   // ker channel = kk*UH*UW + u*UW + v, u==0
      float l = b2[ch];
      const float* wrow = w2 + (size_t)ch * HID_;
#pragma unroll
      for (int c = 0; c < HID_; ++c) l = fmaf(hb[c], wrow[c], l);
      float e = __expf(l);
      sumv[v] += e;
      accv[v] = fmaf(e, nv, accv[v]);
    }
  }

#pragma unroll
  for (int v = 0; v < UWF; ++v) {
    float o = (accv[v] / sumv[v]) * wps + bps;
    size_t base = (size_t)h * OW + (size_t)w * UWF + v;
#pragma unroll
    for (int c = 0; c < 3; ++c) {
      out[(size_t)(b * 3 + c) * OPL + base] = o;
    }
  }
}

extern "C" void kernel_launch(void* const* d_in, const int* in_sizes, int n_in,
                              void* d_out, int out_size, void* d_ws, size_t ws_size,
                              hipStream_t stream) {
  const float* x  = (const float*)d_in[0];
  const float* w1 = (const float*)d_in[1];
  const float* b1 = (const float*)d_in[2];
  const float* w2 = (const float*)d_in[3];
  const float* b2 = (const float*)d_in[4];
  const float* wp = (const float*)d_in[5];
  const float* bp = (const float*)d_in[6];
  float* out = (float*)d_out;

  const int total  = BB * HW;              // 1,048,576
  const int block  = 256;
  const int grid   = total / block;        // 4096, exact

  const size_t xg_bytes = (size_t)total * sizeof(float);
  if (ws_size >= xg_bytes) {
    float* xg = (float*)d_ws;
    xg_mean_kernel<<<grid, block, 0, stream>>>(x, xg);
    carafe_fused_kernel<true><<<grid, block, 0, stream>>>(x, xg, w1, b1, w2, b2, wp, bp, out);
  } else {
    carafe_fused_kernel<false><<<grid, block, 0, stream>>>(x, nullptr, w1, b1, w2, b2, wp, bp, out);
  }
}

// Round 3
// 126.818 us; speedup vs baseline: 1.4966x; 1.4966x over previous
//
#include <hip/hip_runtime.h>

typedef __attribute__((ext_vector_type(8))) short bf16x8;
typedef __attribute__((ext_vector_type(4))) float f32x4;

namespace {
constexpr int KS = 5, UWF = 3, HID = 64;
constexpr int BB = 4, HH = 512, WW = 512;
constexpr int HW = HH * WW;
constexpr int OW = WW * UWF;      // 1536
constexpr int OPL = HH * OW;      // 786432
constexpr size_t XG_BYTES = (size_t)BB * HW * sizeof(float);   // 4 MB
constexpr size_t W1P_ELEMS = 64 * 32;    // bf16, bias folded at k=9
constexpr size_t W2P_ELEMS = 80 * 64;    // bf16, padded 75->80 channels
}

__device__ __forceinline__ ushort f2bf(float f) {   // round-to-nearest-even
  unsigned u = __builtin_bit_cast(unsigned, f);
  u += 0x7fffu + ((u >> 16) & 1u);
  return (ushort)(u >> 16);
}

__global__ __launch_bounds__(256) void xg_mean_kernel(const float* __restrict__ x,
                                                      float* __restrict__ xg) {
  int idx = blockIdx.x * 256 + threadIdx.x;
  int b = idx >> 18;
  int hw = idx & (HW - 1);
  const float* xb = x + (size_t)b * 3 * HW;
  xg[idx] = (xb[hw] + xb[HW + hw] + xb[2 * HW + hw]) * (1.0f / 3.0f);
}

__global__ __launch_bounds__(256) void prep_weights(
    const float* __restrict__ w1, const float* __restrict__ b1,
    const float* __restrict__ w2, ushort* __restrict__ w1p,
    ushort* __restrict__ w2p) {
  int tid = threadIdx.x;
  for (int idx = tid; idx < (int)W1P_ELEMS; idx += 256) {
    int ch = idx >> 5, k = idx & 31;
    float v = (k < 9) ? w1[ch * 9 + k] : ((k == 9) ? b1[ch] : 0.0f);
    w1p[idx] = f2bf(v);
  }
  for (int idx = tid; idx < (int)W2P_ELEMS; idx += 256) {
    int ch = idx >> 6, k = idx & 63;
    float v = (ch < 75) ? w2[ch * 64 + k] : 0.0f;
    w2p[idx] = f2bf(v);
  }
}

// Block = 64 consecutive pixels of one row (4 waves x 16 px). Per wave:
// conv1 (im2col K=10 pad 32) 4 MFMAs -> hb bf16 in swizzled LDS ->
// conv2 (K=64) 10 MFMAs -> logits LDS -> scalar softmax+reassembly epilogue.
__global__ __launch_bounds__(256) void carafe_mfma(
    const float* __restrict__ xg, const ushort* __restrict__ w1p,
    const ushort* __restrict__ w2p, const float* __restrict__ b2,
    const float* __restrict__ wp, const float* __restrict__ bp,
    float* __restrict__ out) {
  __shared__ __align__(16) float xg_s[5][68];
  __shared__ __align__(16) ushort hb_s[4][16 * 64];   // [wave][row(px)*64 + swz]
  __shared__ __align__(16) float logit_s[4][16][84];  // stride 84 vs bank conflicts

  const int tid = threadIdx.x;
  const int wv = tid >> 6, l = tid & 63;
  const int g = l >> 4, n = l & 15;

  const int gpix0 = blockIdx.x * 64;
  const int b = gpix0 >> 18;
  const int hw0 = gpix0 & (HW - 1);
  const int h = hw0 >> 9, wb = hw0 & (WW - 1);

  // stage xg strip: rows h-2..h+2, cols wb-2..wb+65 (zero-padded)
  for (int i = tid; i < 5 * 68; i += 256) {
    int r = i / 68, cc = i - r * 68;
    int y = h + r - 2, xx = wb + cc - 2;
    float v = 0.0f;
    if ((unsigned)y < (unsigned)HH && (unsigned)xx < (unsigned)WW)
      v = xg[((size_t)b << 18) + (y << 9) + xx];
    xg_s[r][cc] = v;
  }
  __syncthreads();

  // ---- conv1: A = per-pixel patch, k = ky*3+kx (k<9), k=9 bias input 1.0
  bf16x8 a1 = {0, 0, 0, 0, 0, 0, 0, 0};
  const int col0 = wv * 16 + n + 2;   // xg_s col of this pixel's center
  if (g == 0) {
#pragma unroll
    for (int j = 0; j < 8; ++j) {
      int ky = j / 3, kx = j - ky * 3;
      a1[j] = (short)f2bf(xg_s[ky + 1][col0 + kx - 1]);
    }
  } else if (g == 1) {
    a1[0] = (short)f2bf(xg_s[3][col0 + 1]);  // k=8: ky=2,kx=2
    a1[1] = (short)0x3F80;                   // k=9: bias input = 1.0
  }
  f32x4 zero = {0.f, 0.f, 0.f, 0.f};

#pragma unroll
  for (int t = 0; t < 4; ++t) {
    bf16x8 bf = *reinterpret_cast<const bf16x8*>(w1p + (t * 16 + n) * 32 + g * 8);
    f32x4 acc = __builtin_amdgcn_mfma_f32_16x16x32_bf16(a1, bf, zero, 0, 0, 0);
#pragma unroll
    for (int r = 0; r < 4; ++r) {      // C: row m=(l>>4)*4+r, col ch=t*16+n
      int m = g * 4 + r;
      int ch = t * 16 + n;
      float hv = fmaxf(acc[r], 0.0f);
      int chunk = (ch >> 3) ^ (m & 7);     // XOR swizzle (16B chunks)
      hb_s[wv][m * 64 + chunk * 8 + (ch & 7)] = f2bf(hv);
    }
  }
  __syncthreads();

  // ---- conv2: A row = pixel (l&15), k = g*8 + 32*s (+j), read swizzled
  bf16x8 a2[2];
#pragma unroll
  for (int s = 0; s < 2; ++s) {
    int chunk = (g + 4 * s) ^ (n & 7);
    a2[s] = *reinterpret_cast<const bf16x8*>(&hb_s[wv][n * 64 + chunk * 8]);
  }
#pragma unroll
  for (int t = 0; t < 5; ++t) {
    const ushort* wrow = w2p + (t * 16 + n) * 64 + g * 8;
    bf16x8 bf0 = *reinterpret_cast<const bf16x8*>(wrow);
    bf16x8 bf1 = *reinterpret_cast<const bf16x8*>(wrow + 32);
    f32x4 acc = __builtin_amdgcn_mfma_f32_16x16x32_bf16(a2[0], bf0, zero, 0, 0, 0);
    acc = __builtin_amdgcn_mfma_f32_16x16x32_bf16(a2[1], bf1, acc, 0, 0, 0);
#pragma unroll
    for (int r = 0; r < 4; ++r)
      logit_s[wv][g * 4 + r][t * 16 + n] = acc[r];
  }
  __syncthreads();

  // ---- epilogue: lane -> (pixel, v); softmax over 25 taps + reassembly
  const int epx = l >> 2, ev = l & 3;
  if (ev < 3) {
    float accv = 0.f, sumv = 0.f;
    const int wcol = wv * 16 + epx;   // tap col = wcol + dx (xg_s origin -2)
#pragma unroll
    for (int kk = 0; kk < 25; ++kk) {
      int ch = kk * 3 + ev;
      float lg = logit_s[wv][epx][ch] + b2[ch];
      float e = __expf(lg);           // logits tiny: no max-sub needed
      sumv += e;
      int dy = kk / 5, dx = kk - dy * 5;
      float nv = xg_s[dy][wcol + dx];
      accv = fmaf(e, nv, accv);
    }
    float o = (accv / sumv) * wp[0] + bp[0];
    int w = wb + wv * 16 + epx;
    size_t base = (size_t)h * OW + (size_t)w * UWF + ev;
    float* op = out + (size_t)b * 3 * OPL + base;
    op[0] = o;
    op[OPL] = o;
    op[2 * (size_t)OPL] = o;
  }
}

// Fallback (ws too small): round-1 fused per-pixel kernel, fp32 VALU.
__global__ __launch_bounds__(256) void carafe_fused_fallback(
    const float* __restrict__ x,
    const float* __restrict__ w1, const float* __restrict__ b1,
    const float* __restrict__ w2, const float* __restrict__ b2,
    const float* __restrict__ wp, const float* __restrict__ bp,
    float* __restrict__ out) {
  int idx = blockIdx.x * 256 + threadIdx.x;
  int b = idx >> 18;
  int hw = idx & (HW - 1);
  int h = hw >> 9;
  int w = hw & (WW - 1);
  float wps = wp[0], bps = bp[0];
  float xw[KS][KS];
#pragma unroll
  for (int dy = 0; dy < KS; ++dy) {
    int y = h + dy - 2;
    bool yok = ((unsigned)y < (unsigned)HH);
#pragma unroll
    for (int dx = 0; dx < KS; ++dx) {
      int xc = w + dx - 2;
      bool ok = yok && ((unsigned)xc < (unsigned)WW);
      float v = 0.0f;
      if (ok) {
        const float* xb = x + (size_t)b * 3 * HW + y * WW + xc;
        v = (xb[0] + xb[HW] + xb[2 * HW]) * (1.0f / 3.0f);
      }
      xw[dy][dx] = v;
    }
  }
  float hb[HID];
#pragma unroll
  for (int c = 0; c < HID; ++c) {
    float acc = b1[c];
#pragma unroll
    for (int ky = 0; ky < 3; ++ky)
#pragma unroll
      for (int kx = 0; kx < 3; ++kx)
        acc = fmaf(xw[1 + ky][1 + kx], w1[c * 9 + ky * 3 + kx], acc);
    hb[c] = fmaxf(acc, 0.0f);
  }
  float accv[UWF] = {0.f, 0.f, 0.f};
  float sumv[UWF] = {0.f, 0.f, 0.f};
#pragma unroll
  for (int kk = 0; kk < KS * KS; ++kk) {
    float nv = xw[kk / KS][kk % KS];
#pragma unroll
    for (int v = 0; v < UWF; ++v) {
      int ch = kk * UWF + v;
      float lg = b2[ch];
      const float* wrow = w2 + (size_t)ch * HID;
#pragma unroll
      for (int c = 0; c < HID; ++c) lg = fmaf(hb[c], wrow[c], lg);
      float e = __expf(lg);
      sumv[v] += e;
      accv[v] = fmaf(e, nv, accv[v]);
    }
  }
#pragma unroll
  for (int v = 0; v < UWF; ++v) {
    float o = (accv[v] / sumv[v]) * wps + bps;
    size_t base = (size_t)h * OW + (size_t)w * UWF + v;
#pragma unroll
    for (int c = 0; c < 3; ++c) out[(size_t)(b * 3 + c) * OPL + base] = o;
  }
}

extern "C" void kernel_launch(void* const* d_in, const int* in_sizes, int n_in,
                              void* d_out, int out_size, void* d_ws, size_t ws_size,
                              hipStream_t stream) {
  const float* x  = (const float*)d_in[0];
  const float* w1 = (const float*)d_in[1];
  const float* b1 = (const float*)d_in[2];
  const float* w2 = (const float*)d_in[3];
  const float* b2 = (const float*)d_in[4];
  const float* wp = (const float*)d_in[5];
  const float* bp = (const float*)d_in[6];
  float* out = (float*)d_out;

  const size_t need = XG_BYTES + (W1P_ELEMS + W2P_ELEMS) * sizeof(ushort);
  if (ws_size >= need) {
    float*  xgp = (float*)d_ws;
    ushort* w1p = (ushort*)((char*)d_ws + XG_BYTES);
    ushort* w2p = w1p + W1P_ELEMS;
    xg_mean_kernel<<<BB * HW / 256, 256, 0, stream>>>(x, xgp);
    prep_weights<<<1, 256, 0, stream>>>(w1, b1, w2, w1p, w2p);
    carafe_mfma<<<BB * HW / 64, 256, 0, stream>>>(xgp, w1p, w2p, b2, wp, bp, out);
  } else {
    carafe_fused_fallback<<<BB * HW / 256, 256, 0, stream>>>(x, w1, b1, w2, b2, wp, bp, out);
  }
}

// Round 5
// 63.488 us; speedup vs baseline: 2.9894x; 1.9975x over previous
//
#include <hip/hip_runtime.h>

typedef __attribute__((ext_vector_type(8))) short bf16x8;
typedef __attribute__((ext_vector_type(4))) float f32x4;

namespace {
constexpr int KS = 5, UWF = 3, HID = 64;
constexpr int BB = 4, HH = 512, WW = 512;
constexpr int HW = HH * WW;
constexpr int OW = WW * UWF;      // 1536
constexpr int OPL = HH * OW;      // 786432
constexpr float LOG2E = 1.44269504088896340736f;

constexpr int PXB = 256;          // pixels per block (4 waves x 64 px)
constexpr int XGC = PXB + 5;      // 261 staged cols (2+256+2, +1 slack)
constexpr int HBS = 72;           // hb row stride in bf16 elems (16B-aligned rows)
constexpr int LGS = 84;           // e/logit row stride in f32 (2-way banks only)

constexpr size_t XG_BYTES = (size_t)BB * HW * sizeof(float);   // 4 MB
constexpr size_t W1P_ELEMS = 64 * 32;    // bf16: k=g*8+j; j<3,g<3 -> tap(ky=g,kx=j); k=24 -> bias
constexpr size_t W2P_ELEMS = 80 * 64;    // bf16, padded 75->80 ch, pre-scaled by log2e
constexpr size_t B2P_ELEMS = 80;         // f32, pre-scaled by log2e, 0-padded
}

__device__ __forceinline__ ushort f2bf(float f) {   // round-half-up (bias ~2^-17, negligible)
  unsigned u = __builtin_bit_cast(unsigned, f);
  return (ushort)((u + 0x8000u) >> 16);
}

__global__ __launch_bounds__(256) void xg_mean_kernel(const float* __restrict__ x,
                                                      float* __restrict__ xg) {
  int idx = blockIdx.x * 256 + threadIdx.x;
  int b = idx >> 18;
  int hw = idx & (HW - 1);
  const float* xb = x + (size_t)b * 3 * HW;
  xg[idx] = (xb[hw] + xb[HW + hw] + xb[2 * HW + hw]) * (1.0f / 3.0f);
}

__global__ __launch_bounds__(256) void prep_weights(
    const float* __restrict__ w1, const float* __restrict__ b1,
    const float* __restrict__ w2, const float* __restrict__ b2,
    ushort* __restrict__ w1p, ushort* __restrict__ w2p, float* __restrict__ b2p) {
  int idx = blockIdx.x * 256 + threadIdx.x;
  if (idx < (int)W1P_ELEMS) {
    int ch = idx >> 5, k = idx & 31, g = k >> 3, j = k & 7;
    float v = 0.0f;
    if (g < 3 && j < 3) v = w1[ch * 9 + g * 3 + j];
    else if (k == 24)   v = b1[ch];
    w1p[idx] = f2bf(v);
  } else if (idx < (int)(W1P_ELEMS + W2P_ELEMS)) {
    int i2 = idx - (int)W1P_ELEMS;
    int ch = i2 >> 6, k = i2 & 63;
    w2p[i2] = (ch < 75) ? f2bf(w2[ch * 64 + k] * LOG2E) : (ushort)0;
  } else if (idx < (int)(W1P_ELEMS + W2P_ELEMS + B2P_ELEMS)) {
    int ch = idx - (int)(W1P_ELEMS + W2P_ELEMS);
    b2p[ch] = (ch < 75) ? b2[ch] * LOG2E : 0.0f;
  }
}

// Block = 256 consecutive pixels of one row; 4 waves x 64 px (4 M-tiles of 16).
// Per wave: resident B-frags/bias in regs; per M-tile: conv1 (4 MFMA) -> hb
// (wave-private LDS, bf16) -> conv2 (10 MFMA, acc init = b2*log2e) -> exp2 ->
// e (wave-private LDS, f32) -> epilogue (softmax-normalize + reassembly).
// Single __syncthreads (after xg staging); all other LDS traffic is wave-private.
__global__ __launch_bounds__(256, 4) void carafe_mfma(
    const float* __restrict__ xg, const ushort* __restrict__ w1p,
    const ushort* __restrict__ w2p, const float* __restrict__ b2p,
    const float* __restrict__ wp, const float* __restrict__ bp,
    float* __restrict__ out) {
  __shared__ __align__(16) float xg_s[5][XGC];
  __shared__ __align__(16) ushort hb_s[4][16 * HBS];
  __shared__ __align__(16) float e_s[4][16 * LGS];

  const int tid = threadIdx.x;
  const int wv = tid >> 6, l = tid & 63;
  const int g = l >> 4, n = l & 15;

  const int gpix0 = blockIdx.x * PXB;
  const int b = gpix0 >> 18;
  const int h = (gpix0 >> 9) & (HH - 1);
  const int wb = gpix0 & (WW - 1);   // 0 or 256

  // stage xg strip: rows h-2..h+2, cols wb-2..wb+258 (zero-padded)
  for (int i = tid; i < 5 * XGC; i += 256) {
    int r = i / XGC, cc = i - r * XGC;
    int y = h + r - 2, xx = wb + cc - 2;
    float v = 0.0f;
    if ((unsigned)y < (unsigned)HH && (unsigned)xx < (unsigned)WW)
      v = xg[((size_t)b << 18) + (y << 9) + xx];
    xg_s[r][cc] = v;
  }

  // wave-resident weights (global/L2 loads overlap the staging)
  bf16x8 wf1[4], wf2[10];
  float b2v[5];
#pragma unroll
  for (int t = 0; t < 4; ++t)
    wf1[t] = *reinterpret_cast<const bf16x8*>(w1p + (t * 16 + n) * 32 + g * 8);
#pragma unroll
  for (int t = 0; t < 5; ++t) {
    const ushort* wrow = w2p + (t * 16 + n) * 64 + g * 8;
    wf2[2 * t]     = *reinterpret_cast<const bf16x8*>(wrow);
    wf2[2 * t + 1] = *reinterpret_cast<const bf16x8*>(wrow + 32);
    b2v[t] = b2p[t * 16 + n];
  }
  const float wps = wp[0], bps = bp[0];
  __syncthreads();

  ushort* hbw = hb_s[wv];
  float*  ew  = e_s[wv];

#pragma unroll
  for (int mt = 0; mt < 4; ++mt) {
    const int px0 = wv * 64 + mt * 16;   // block-local col of this M-tile's first px

    // ---- conv1 A-frag: k=g*8+j; g<3,j<3 -> tap(ky=g,kx=j); g==3,j==0 -> 1.0 (bias)
    bf16x8 a1 = {0, 0, 0, 0, 0, 0, 0, 0};
    if (g < 3) {
      const float* row = &xg_s[1 + g][px0 + n + 1];
      a1[0] = (short)f2bf(row[0]);
      a1[1] = (short)f2bf(row[1]);
      a1[2] = (short)f2bf(row[2]);
    } else {
      a1[0] = (short)0x3F80;   // 1.0bf
    }

    // ---- conv1: 4 MFMAs -> relu -> bf16 -> wave-private LDS
#pragma unroll
    for (int t = 0; t < 4; ++t) {
      f32x4 zero = {0.f, 0.f, 0.f, 0.f};
      f32x4 acc = __builtin_amdgcn_mfma_f32_16x16x32_bf16(a1, wf1[t], zero, 0, 0, 0);
      int chb = t * 16 + n;
#pragma unroll
      for (int r = 0; r < 4; ++r)
        hbw[(g * 4 + r) * HBS + chb] = f2bf(fmaxf(acc[r], 0.0f));
    }

    // ---- conv2: A from hb LDS, acc init = b2*log2e, 10 MFMAs, exp2 -> e LDS
    bf16x8 a2a = *reinterpret_cast<const bf16x8*>(hbw + n * HBS + g * 8);
    bf16x8 a2b = *reinterpret_cast<const bf16x8*>(hbw + n * HBS + 32 + g * 8);
#pragma unroll
    for (int t = 0; t < 5; ++t) {
      f32x4 acc = {b2v[t], b2v[t], b2v[t], b2v[t]};
      acc = __builtin_amdgcn_mfma_f32_16x16x32_bf16(a2a, wf2[2 * t], acc, 0, 0, 0);
      acc = __builtin_amdgcn_mfma_f32_16x16x32_bf16(a2b, wf2[2 * t + 1], acc, 0, 0, 0);
      int chb = t * 16 + n;
#pragma unroll
      for (int r = 0; r < 4; ++r)
        ew[(g * 4 + r) * LGS + chb] = exp2f(acc[r]);
    }

    // ---- epilogue: lane -> (px, v); normalize + reassemble + store 3 channels
    const int epx = l >> 2, ev = l & 3;
    if (ev < 3) {
      float s0 = 0.f, s1 = 0.f, a0 = 0.f, a1v = 0.f;
      const float* erow = ew + epx * LGS;
      const int cc0 = px0 + epx;
#pragma unroll
      for (int kk = 0; kk < 25; ++kk) {
        int dy = kk / 5, dx = kk - dy * 5;
        float e = erow[3 * kk + ev];
        float nv = xg_s[dy][cc0 + dx];
        if (kk & 1) { s1 += e; a1v = fmaf(e, nv, a1v); }
        else        { s0 += e; a0  = fmaf(e, nv, a0);  }
      }
      float o = ((a0 + a1v) / (s0 + s1)) * wps + bps;
      int wglob = wb + px0 + epx;
      float* op = out + (size_t)b * 3 * OPL + (size_t)h * OW + (size_t)wglob * 3 + ev;
      op[0] = o;
      op[OPL] = o;
      op[2 * (size_t)OPL] = o;
    }
  }
}

extern "C" void kernel_launch(void* const* d_in, const int* in_sizes, int n_in,
                              void* d_out, int out_size, void* d_ws, size_t ws_size,
                              hipStream_t stream) {
  const float* x  = (const float*)d_in[0];
  const float* w1 = (const float*)d_in[1];
  const float* b1 = (const float*)d_in[2];
  const float* w2 = (const float*)d_in[3];
  const float* b2 = (const float*)d_in[4];
  const float* wp = (const float*)d_in[5];
  const float* bp = (const float*)d_in[6];
  float* out = (float*)d_out;

  const size_t need = XG_BYTES + (W1P_ELEMS + W2P_ELEMS) * sizeof(ushort)
                      + B2P_ELEMS * sizeof(float);
  if (ws_size >= need) {
    float*  xgp = (float*)d_ws;
    ushort* w1p = (ushort*)((char*)d_ws + XG_BYTES);
    ushort* w2p = w1p + W1P_ELEMS;
    float*  b2p = (float*)(w2p + W2P_ELEMS);
    xg_mean_kernel<<<BB * HW / 256, 256, 0, stream>>>(x, xgp);
    const int prep_total = (int)(W1P_ELEMS + W2P_ELEMS + B2P_ELEMS);
    prep_weights<<<(prep_total + 255) / 256, 256, 0, stream>>>(w1, b1, w2, b2, w1p, w2p, b2p);
    carafe_mfma<<<BB * HW / PXB, 256, 0, stream>>>(xgp, w1p, w2p, b2p, wp, bp, out);
  } else {
    // fallback: fully-fused per-pixel fp32 kernel (round-1 version)
    // (ws always large enough in practice; kept for safety)
    xg_mean_kernel<<<1, 1, 0, stream>>>(x, (float*)d_ws);  // no-op-ish guard; not expected
  }
}

// Round 7
// 56.972 us; speedup vs baseline: 3.3313x; 1.1144x over previous
//
#include <hip/hip_runtime.h>

typedef __attribute__((ext_vector_type(8))) short bf16x8;
typedef __attribute__((ext_vector_type(4))) float f32x4;

namespace {
constexpr int UWF = 3, BB = 4, HH = 512, WW = 512;
constexpr int HW = HH * WW;
constexpr int OW = WW * UWF;      // 1536
constexpr int OPL = HH * OW;      // 786432
constexpr float LOG2E = 1.44269504088896340736f;

constexpr int PXB = 128;          // px per block (2 waves x 64 px)
constexpr int XGC = 133;          // staged cols (2+128+2, +1 slack)
constexpr int XGS = 134;          // xg row stride (dwords)
constexpr int HBS = 72;           // hb row stride (ushorts; 144B, 16B-aligned, conflict-free b128)
constexpr int ES  = 100;          // e row stride (dwords); slots kk*4+v, pad v=3 unread, slot 99=dump

constexpr int W1L_ELEMS = 64 * 32;   // ushort, lane-major conv1 frags
constexpr int W2L_ELEMS = 64 * 80;   // ushort, lane-major conv2 frags (pre-scaled log2e)
constexpr int B2L_ELEMS = 64 * 8;    // f32, lane-major b2*log2e (pad to 8)
}

__device__ __forceinline__ ushort f2bf(float f) {   // round-half-up
  unsigned u = __builtin_bit_cast(unsigned, f);
  return (ushort)((u + 0x8000u) >> 16);
}

// Lane-major weight prep: lane l=(g,n) g=l>>4, n=l&15.
// conv1 frag t elem j <-> B[k=g*8+j][ch=t*16+n]; g<3,j<3 tap(g,j); k==24 bias.
// conv2 frag tt=(t,s) elem j <-> B[k=s*32+g*8+j][ch=t*16+n], scaled by log2e.
__global__ __launch_bounds__(256) void prep_weights(
    const float* __restrict__ w1, const float* __restrict__ b1,
    const float* __restrict__ w2, const float* __restrict__ b2,
    ushort* __restrict__ w1L, ushort* __restrict__ w2L, float* __restrict__ b2L) {
  int idx = blockIdx.x * 256 + threadIdx.x;
  if (idx < W1L_ELEMS) {
    int l = idx >> 5, t = (idx >> 3) & 3, j = idx & 7;
    int g = l >> 4, n = l & 15;
    int ch = t * 16 + n;
    float v = 0.0f;
    if (g < 3 && j < 3) v = w1[ch * 9 + g * 3 + j];
    else if (g == 3 && j == 0) v = b1[ch];
    w1L[idx] = f2bf(v);
  } else if (idx < W1L_ELEMS + W2L_ELEMS) {
    int i2 = idx - W1L_ELEMS;
    int l = i2 / 80, rem = i2 - l * 80, tt = rem >> 3, j = rem & 7;
    int g = l >> 4, n = l & 15;
    int t = tt >> 1, s = tt & 1;
    int ch = t * 16 + n, k = s * 32 + g * 8 + j;
    w2L[i2] = (ch < 75) ? f2bf(w2[ch * 64 + k] * LOG2E) : (ushort)0;
  } else if (idx < W1L_ELEMS + W2L_ELEMS + B2L_ELEMS) {
    int i3 = idx - W1L_ELEMS - W2L_ELEMS;
    int l = i3 >> 3, t = i3 & 7;
    int ch = t * 16 + (l & 15);
    b2L[i3] = (t < 5 && ch < 75) ? b2[ch] * LOG2E : 0.0f;
  }
}

// Block = 128 px of one row (2 waves x 64 px; 4 M-tiles of 16 per wave).
// Staging computes channel-mean inline (no xg pass). Per M-tile:
// conv1 (4 MFMA) -> hb bf16 LDS -> conv2 (10 MFMA, acc=b2*log2e) -> exp2 ->
// e in kk-padded-4 LDS layout -> epilogue (static-offset reads, rcp, store).
__global__ __launch_bounds__(128, 4) void carafe_mfma(
    const float* __restrict__ x, const ushort* __restrict__ w1L,
    const ushort* __restrict__ w2L, const float* __restrict__ b2L,
    const float* __restrict__ wp, const float* __restrict__ bp,
    float* __restrict__ out) {
  __shared__ __align__(16) float xg_s[5][XGS];
  __shared__ __align__(16) ushort hb_s[2][16 * HBS];
  __shared__ __align__(16) float e_s[2][16 * ES];

  const int tid = threadIdx.x;
  const int wv = tid >> 6, l = tid & 63;
  const int g = l >> 4, n = l & 15;

  const int gpix0 = blockIdx.x * PXB;
  const int b = gpix0 >> 18;
  const int h = (gpix0 >> 9) & (HH - 1);
  const int wb = gpix0 & (WW - 1);

  // fused staging: rows h-2..h+2, cols wb-2..wb+130, channel-mean of x
  const float* xb = x + (size_t)b * 3 * HW;
  for (int i = tid; i < 5 * XGC; i += 128) {
    int r = i / XGC, cc = i - r * XGC;
    int y = h + r - 2, xx = wb + cc - 2;
    float v = 0.0f;
    if ((unsigned)y < (unsigned)HH && (unsigned)xx < (unsigned)WW) {
      const float* p = xb + y * WW + xx;
      v = (p[0] + p[HW] + p[2 * HW]) * (1.0f / 3.0f);
    }
    xg_s[r][cc] = v;
  }

  // lane-major weights: 14 contiguous b128 + 2 f32x4 per lane
  bf16x8 wf1[4], wf2[10];
  const ushort* p1 = w1L + l * 32;
#pragma unroll
  for (int t = 0; t < 4; ++t) wf1[t] = *reinterpret_cast<const bf16x8*>(p1 + t * 8);
  const ushort* p2 = w2L + l * 80;
#pragma unroll
  for (int t = 0; t < 10; ++t) wf2[t] = *reinterpret_cast<const bf16x8*>(p2 + t * 8);
  f32x4 b2a = *reinterpret_cast<const f32x4*>(b2L + l * 8);
  const float b2t4 = b2L[l * 8 + 4];
  const float wps = wp[0], bps = bp[0];
  __syncthreads();

  ushort* hbw = hb_s[wv];
  float* ew = e_s[wv];

#pragma unroll
  for (int mt = 0; mt < 4; ++mt) {
    const int px0 = wv * 64 + mt * 16;

    // conv1 A-frag: k=g*8+j; g<3,j<3 -> tap; g==3,j==0 -> 1.0 (bias input)
    bf16x8 a1 = {0, 0, 0, 0, 0, 0, 0, 0};
    if (g < 3) {
      const float* row = &xg_s[1 + g][px0 + n + 1];
      a1[0] = (short)f2bf(row[0]);
      a1[1] = (short)f2bf(row[1]);
      a1[2] = (short)f2bf(row[2]);
    } else {
      a1[0] = (short)0x3F80;
    }

    f32x4 zero = {0.f, 0.f, 0.f, 0.f};
#pragma unroll
    for (int t = 0; t < 4; ++t) {
      f32x4 acc = __builtin_amdgcn_mfma_f32_16x16x32_bf16(a1, wf1[t], zero, 0, 0, 0);
#pragma unroll
      for (int r = 0; r < 4; ++r)
        hbw[(g * 4 + r) * HBS + t * 16 + n] = f2bf(fmaxf(acc[r], 0.0f));
    }

    bf16x8 a2a = *reinterpret_cast<const bf16x8*>(hbw + n * HBS + g * 8);
    bf16x8 a2b = *reinterpret_cast<const bf16x8*>(hbw + n * HBS + 32 + g * 8);
#pragma unroll
    for (int t = 0; t < 5; ++t) {
      float bini = (t < 4) ? b2a[t] : b2t4;
      f32x4 acc = {bini, bini, bini, bini};
      acc = __builtin_amdgcn_mfma_f32_16x16x32_bf16(a2a, wf2[2 * t], acc, 0, 0, 0);
      acc = __builtin_amdgcn_mfma_f32_16x16x32_bf16(a2b, wf2[2 * t + 1], acc, 0, 0, 0);
      int ch = t * 16 + n;
      int kk = (ch * 171) >> 9;            // exact ch/3 for ch<512
      int ch4 = kk * 4 + (ch - kk * 3);    // kk*4 + v
      if (t == 4 && n >= 11) ch4 = 99;     // ch 75..79 -> dump slot (kk24 pad, never read)
#pragma unroll
      for (int r = 0; r < 4; ++r)
        ew[(g * 4 + r) * ES + ch4] = exp2f(acc[r]);
    }

    // epilogue: lane -> (px, v); all offsets compile-time constants
    const int epx = l >> 2, ev = l & 3;
    if (ev < 3) {
      const float* erow = ew + epx * ES + ev;
      const float* nb = &xg_s[0][px0 + epx];
      float num = 0.f, den = 0.f;
#pragma unroll
      for (int kk = 0; kk < 25; ++kk) {
        int dy = kk / 5, dx = kk - dy * 5;
        float e = erow[4 * kk];
        float nv = nb[dy * XGS + dx];
        num = fmaf(e, nv, num);
        den += e;
      }
      float o = num * __builtin_amdgcn_rcpf(den) * wps + bps;
      int wg = wb + px0 + epx;
      float* op = out + (size_t)b * 3 * OPL + (size_t)h * OW + wg * 3 + ev;
      op[0] = o;
      op[OPL] = o;
      op[2 * (size_t)OPL] = o;
    }
  }
}

// Fallback (ws too small; not expected): fused per-pixel fp32 kernel.
__global__ __launch_bounds__(256) void carafe_fused_fallback(
    const float* __restrict__ x,
    const float* __restrict__ w1, const float* __restrict__ b1,
    const float* __restrict__ w2, const float* __restrict__ b2,
    const float* __restrict__ wp, const float* __restrict__ bp,
    float* __restrict__ out) {
  int idx = blockIdx.x * 256 + threadIdx.x;
  int b = idx >> 18;
  int hw = idx & (HW - 1);
  int h = hw >> 9;
  int w = hw & (WW - 1);
  float xw[5][5];
#pragma unroll
  for (int dy = 0; dy < 5; ++dy) {
    int y = h + dy - 2;
#pragma unroll
    for (int dx = 0; dx < 5; ++dx) {
      int xc = w + dx - 2;
      float v = 0.0f;
      if ((unsigned)y < (unsigned)HH && (unsigned)xc < (unsigned)WW) {
        const float* xb = x + (size_t)b * 3 * HW + y * WW + xc;
        v = (xb[0] + xb[HW] + xb[2 * HW]) * (1.0f / 3.0f);
      }
      xw[dy][dx] = v;
    }
  }
  float hb[64];
#pragma unroll
  for (int c = 0; c < 64; ++c) {
    float acc = b1[c];
#pragma unroll
    for (int ky = 0; ky < 3; ++ky)
#pragma unroll
      for (int kx = 0; kx < 3; ++kx)
        acc = fmaf(xw[1 + ky][1 + kx], w1[c * 9 + ky * 3 + kx], acc);
    hb[c] = fmaxf(acc, 0.0f);
  }
  float accv[3] = {0.f, 0.f, 0.f}, sumv[3] = {0.f, 0.f, 0.f};
#pragma unroll
  for (int kk = 0; kk < 25; ++kk) {
    float nv = xw[kk / 5][kk % 5];
#pragma unroll
    for (int v = 0; v < 3; ++v) {
      int ch = kk * 3 + v;
      float lg = b2[ch];
      const float* wrow = w2 + (size_t)ch * 64;
#pragma unroll
      for (int c = 0; c < 64; ++c) lg = fmaf(hb[c], wrow[c], lg);
      float e = __expf(lg);
      sumv[v] += e;
      accv[v] = fmaf(e, nv, accv[v]);
    }
  }
#pragma unroll
  for (int v = 0; v < 3; ++v) {
    float o = (accv[v] / sumv[v]) * wp[0] + bp[0];
    size_t base = (size_t)h * OW + (size_t)w * 3 + v;
#pragma unroll
    for (int c = 0; c < 3; ++c) out[(size_t)(b * 3 + c) * OPL + base] = o;
  }
}

extern "C" void kernel_launch(void* const* d_in, const int* in_sizes, int n_in,
                              void* d_out, int out_size, void* d_ws, size_t ws_size,
                              hipStream_t stream) {
  const float* x  = (const float*)d_in[0];
  const float* w1 = (const float*)d_in[1];
  const float* b1 = (const float*)d_in[2];
  const float* w2 = (const float*)d_in[3];
  const float* b2 = (const float*)d_in[4];
  const float* wp = (const float*)d_in[5];
  const float* bp = (const float*)d_in[6];
  float* out = (float*)d_out;

  const size_t need = (W1L_ELEMS + W2L_ELEMS) * sizeof(ushort) + B2L_ELEMS * sizeof(float);
  if (ws_size >= need) {
    ushort* w1p = (ushort*)d_ws;
    ushort* w2p = w1p + W1L_ELEMS;
    float*  b2p = (float*)(w2p + W2L_ELEMS);
    const int prep_total = W1L_ELEMS + W2L_ELEMS + B2L_ELEMS;
    prep_weights<<<(prep_total + 255) / 256, 256, 0, stream>>>(w1, b1, w2, b2, w1p, w2p, b2p);
    carafe_mfma<<<BB * HW / PXB, 128, 0, stream>>>(x, w1p, w2p, b2p, wp, bp, out);
  } else {
    carafe_fused_fallback<<<BB * HW / 256, 256, 0, stream>>>(x, w1, b1, w2, b2, wp, bp, out);
  }
}